// Round 6
// baseline (1079.344 us; speedup 1.0000x reference)
//
#include <hip/hip_runtime.h>
#include <cstdint>
#include <cstddef>

#define Nn 102400
#define Ff 400
#define Ee 1638400
#define Kk 300
#define Bb 256
#define CAP 64

// XLA/Eigen f32 rational tanh approximation (ElementalIrEmitter::EmitTanh).
// Evaluated with UNFUSED mul/add (XLA emits plain fmul/fadd, no contraction),
// so CPU(np-ref) and this agree bitwise given bit-identical inputs.
__device__ __forceinline__ float xla_tanhf(float x) {
    const float c = 7.90531110763549805f;
    float xc = fminf(fmaxf(x, -c), c);
    float x2 = __fmul_rn(xc, xc);
    float p = -2.76076847742355e-16f;
    p = __fadd_rn(__fmul_rn(p, x2),  2.00018790482477e-13f);
    p = __fadd_rn(__fmul_rn(p, x2), -8.60467152213735e-11f);
    p = __fadd_rn(__fmul_rn(p, x2),  5.12229709037114e-08f);
    p = __fadd_rn(__fmul_rn(p, x2),  1.48572235717979e-05f);
    p = __fadd_rn(__fmul_rn(p, x2),  6.37261928875436e-04f);
    p = __fadd_rn(__fmul_rn(p, x2),  4.89352455891786e-03f);
    p = __fmul_rn(p, xc);
    float q = 1.19825839466702e-06f;
    q = __fadd_rn(__fmul_rn(q, x2), 1.18534705686654e-04f);
    q = __fadd_rn(__fmul_rn(q, x2), 2.26843463243900e-03f);
    q = __fadd_rn(__fmul_rn(q, x2), 4.89352518554385e-03f);
    float r = __fdiv_rn(p, q);
    return (fabsf(x) < 0.0004f) ? x : r;
}

// ---------------- CSR build: 2 edges/thread, padded fill (64B/counter) -------
__global__ void scat_k(const int* __restrict__ ei, int* __restrict__ fill,
                       int* __restrict__ csr) {
    int g = blockIdx.x * 256 + threadIdx.x;
    int2 d2 = *(const int2*)(ei + Ee + 2 * g);
    int e0 = 2 * g, e1 = 2 * g + 1;
    int p0 = atomicAdd(&fill[(size_t)d2.x * 16], 1);
    int p1 = atomicAdd(&fill[(size_t)d2.y * 16], 1);
    if (p0 < CAP) csr[(size_t)d2.x * CAP + p0] = e0;   // edge id, not src
    if (p1 < CAP) csr[(size_t)d2.y * CAP + p1] = e1;
}

// dis = 1/sqrt(deg+1) fp32 (two correctly-rounded ops = XLA-CPU rsqrt
// lowering); compact degree out of the padded counters.
__global__ void dis_k(const int* __restrict__ fill, float* __restrict__ dis,
                      int* __restrict__ degc) {
    int v = blockIdx.x * 256 + threadIdx.x;
    if (v >= Nn) return;
    int d = fill[(size_t)v * 16];
    degc[v] = d;
    dis[v] = 1.0f / sqrtf((float)(d + 1));   // +1 self loop
}

// ---- single-wave fp32 GEMM: [M,K]@[K,64], 32x64 tile, 64 thr, 8x4/thread,
// REGISTER DOUBLE-BUFFERED (ch+1's global loads issue before ch's 512-fma
// block -> HBM latency hides under VALU work) and BARRIER-FREE (1-wave
// workgroup: DS ops are in-order per wave; structure HW-validated r3/r4,
// absmax 0). Per output element: ONE fma per k, k strictly ascending ->
// replicates Eigen gebp. Bit-identical results to the single-buffered form.
template <int CH>   // K = 16*CH
__global__ __launch_bounds__(64) void gemm_w32(const float* __restrict__ A,
                                               const float* __restrict__ B,
                                               float* __restrict__ C) {
    constexpr int K = 16 * CH;
    __shared__ __align__(16) float As[16 * 32];
    __shared__ __align__(16) float Bs[16 * 68];
    int tid = threadIdx.x;
    int tx = tid & 15;            // cols {tx*2, tx*2+1, 32+tx*2, 33+tx*2}
    int ty = tid >> 4;            // rows ty*8..+7
    int base = blockIdx.x * 32;
    int sr = tid >> 1, sh = tid & 1;        // A staging: row sr, k-half sh
    int bk = tid >> 2, bn = (tid & 3) * 16; // B staging: k-row bk, 16 cols
    const float* aip = A + (size_t)(base + sr) * K + sh * 8;
    const float* bip = B + (size_t)bk * 64 + bn;
    float acc[8][4] = {};
    float4 aA0, aA1, aB0, aB1;
    float4 bA[4], bB[4];
    auto LOADG = [&](int ch, float4& a0, float4& a1, float4 (&bv)[4]) {
        const float* ap = aip + ch * 16;
        a0 = *(const float4*)(ap);
        a1 = *(const float4*)(ap + 4);
        const float* bp = bip + (size_t)ch * 16 * 64;
        bv[0] = *(const float4*)(bp);
        bv[1] = *(const float4*)(bp + 4);
        bv[2] = *(const float4*)(bp + 8);
        bv[3] = *(const float4*)(bp + 12);
    };
    auto STORE = [&](const float4& a0, const float4& a1, const float4 (&bv)[4]) {
        As[(sh * 8 + 0) * 32 + sr] = a0.x;
        As[(sh * 8 + 1) * 32 + sr] = a0.y;
        As[(sh * 8 + 2) * 32 + sr] = a0.z;
        As[(sh * 8 + 3) * 32 + sr] = a0.w;
        As[(sh * 8 + 4) * 32 + sr] = a1.x;
        As[(sh * 8 + 5) * 32 + sr] = a1.y;
        As[(sh * 8 + 6) * 32 + sr] = a1.z;
        As[(sh * 8 + 7) * 32 + sr] = a1.w;
        *(float4*)&Bs[bk * 68 + bn]      = bv[0];
        *(float4*)&Bs[bk * 68 + bn + 4]  = bv[1];
        *(float4*)&Bs[bk * 68 + bn + 8]  = bv[2];
        *(float4*)&Bs[bk * 68 + bn + 12] = bv[3];
    };
    auto COMPUTE = [&]() {
#pragma unroll
        for (int kk = 0; kk < 16; ++kk) {
            float4 f0 = *(const float4*)&As[kk * 32 + ty * 8];
            float4 f1 = *(const float4*)&As[kk * 32 + ty * 8 + 4];
            float2 b01 = *(const float2*)&Bs[kk * 68 + tx * 2];
            float2 b23 = *(const float2*)&Bs[kk * 68 + 32 + tx * 2];
            float av[8] = {f0.x, f0.y, f0.z, f0.w, f1.x, f1.y, f1.z, f1.w};
            float bv2[4] = {b01.x, b01.y, b23.x, b23.y};
#pragma unroll
            for (int r = 0; r < 8; ++r)
#pragma unroll
                for (int c = 0; c < 4; ++c) acc[r][c] = fmaf(av[r], bv2[c], acc[r][c]);
        }
    };
    LOADG(0, aA0, aA1, bA);
    int ch = 0;
    while (true) {
        STORE(aA0, aA1, bA);
        if (ch + 1 < CH) LOADG(ch + 1, aB0, aB1, bB);
        COMPUTE();
        if (++ch >= CH) break;
        STORE(aB0, aB1, bB);
        if (ch + 1 < CH) LOADG(ch + 1, aA0, aA1, bA);
        COMPUTE();
        if (++ch >= CH) break;
    }
#pragma unroll
    for (int r = 0; r < 8; ++r) {
        float* cp = C + (size_t)(base + ty * 8 + r) * 64;
        *(float2*)(cp + tx * 2)      = make_float2(acc[r][0], acc[r][1]);
        *(float2*)(cp + 32 + tx * 2) = make_float2(acc[r][2], acc[r][3]);
    }
}

// ------- out = xla_tanh(b + segment_sum(norm_e * t[src_e]) ), fp32 exact-order.
// PHASE 1 additionally does what sortrow_k used to do: bitonic-sort the
// edge-id row (ascending = segment_sum scatter order), gather src = ei[key]
// and dis[src], write the sorted src row + nrm for PHASE 0 reuse. Rows
// padded to a multiple of 32 with nr=0, u=v: fadd(acc, fmul(tv,0)) == acc
// exactly, so remainder loops vanish. fma order UNCHANGED: ascending slots,
// then self-loop.
template <int PHASE>
__global__ __launch_bounds__(256, 4) void agg64_k(const float* __restrict__ t,
                                                  const float* __restrict__ bias,
                                                  const float* __restrict__ dis,
                                                  const int* __restrict__ degc,
                                                  const int* __restrict__ ei,
                                                  int* __restrict__ csr,
                                                  float* __restrict__ nrm,
                                                  float* __restrict__ out,
                                                  const float* __restrict__ W4,
                                                  float* __restrict__ t4) {
    __shared__ int   sidx[4][64];
    __shared__ float snr[4][64];
    int lane = threadIdx.x & 63;
    int wv = __builtin_amdgcn_readfirstlane(threadIdx.x >> 6);
    int v = blockIdx.x * 4 + wv;
    int dv = __builtin_amdgcn_readfirstlane(min(degc[v], CAP));
    float dsv = dis[v];
    float tself = t[(size_t)v * 64 + lane];   // early, independent
    float bsl = bias[lane];                   // early, independent
    int idxl;
    float nr;
    if (PHASE == 1) {
        int key = (lane < dv) ? csr[(size_t)v * CAP + lane] : 0x7FFFFFFF;
        // 64-lane bitonic sort ascending (identical network to old sortrow_k;
        // edge ids are distinct -> deterministic order)
#pragma unroll
        for (int k = 2; k <= 64; k <<= 1) {
#pragma unroll
            for (int j = k >> 1; j; j >>= 1) {
                int other = __shfl_xor(key, j);
                bool up = ((lane & k) == 0);
                bool lower = ((lane & j) == 0);
                key = (lower == up) ? min(key, other) : max(key, other);
            }
        }
        idxl = v;                                    // pad u = v
        if (lane < dv) idxl = ei[key];               // src of that edge
        nr = (lane < dv) ? __fmul_rn(dis[idxl], dsv) : 0.0f;   // pad nr = 0
        csr[(size_t)v * CAP + lane] = idxl;          // sorted src row
        nrm[(size_t)v * 64 + lane] = nr;
    } else {
        idxl = (lane < dv) ? csr[(size_t)v * CAP + lane] : v;
        nr = nrm[(size_t)v * 64 + lane];             // pads are 0
    }
    sidx[wv][lane] = idxl;
    snr[wv][lane] = nr;
    // in-order DS per wave: reads below see the writes above (validated r3/r4)
    int dvp = (dv + 31) & ~31;                // 0, 32, or 64
    float acc = 0.0f;
    for (int j = 0; j < dvp; j += 32) {
        float tv[32], nv[32];
#pragma unroll
        for (int q = 0; q < 32; ++q) {
            int u = __builtin_amdgcn_readfirstlane(sidx[wv][j + q]);
            tv[q] = t[(size_t)u * 64 + lane];
        }
#pragma unroll
        for (int q = 0; q < 32; ++q) nv[q] = snr[wv][j + q];
#pragma unroll
        for (int q = 0; q < 32; ++q)
            acc = __fadd_rn(acc, __fmul_rn(tv[q], nv[q]));   // pads: +0, exact
    }
    // self-loop last (ref appends loops after edges)
    acc = __fadd_rn(acc, __fmul_rn(tself, __fmul_rn(dsv, dsv)));
    float res = xla_tanhf(__fadd_rn(acc, bsl));
    out[(size_t)v * 64 + lane] = res;
    if (W4 != nullptr) {
        // h3 . W4, sequential k=0..63 with FMA (one accumulator)
        float w4l = W4[lane];
        float a4 = 0.0f;
#pragma unroll
        for (int k = 0; k < 64; ++k) {
            float hk = __shfl(res, k);
            float wk = __shfl(w4l, k);
            a4 = fmaf(hk, wk, a4);
        }
        if (lane == 0) t4[v] = a4;
    }
}

__global__ void agg1_k(const float* __restrict__ t4, const float* __restrict__ dis,
                       const int* __restrict__ degc, const int* __restrict__ csr,
                       const float* __restrict__ nrm,
                       const float* __restrict__ b4, float* __restrict__ h4) {
    int v = blockIdx.x * 256 + threadIdx.x;
    if (v >= Nn) return;
    int dv = min(degc[v], CAP);
    float dsv = dis[v];
    const int* row = csr + (size_t)v * CAP;
    const float* nr = nrm + (size_t)v * 64;
    float acc = 0.0f;
    int j = 0;
    for (; j + 16 <= dv; j += 16) {
        int u[16]; float nv[16], tv[16];
#pragma unroll
        for (int q = 0; q < 16; ++q) nv[q] = nr[j + q];     // independent of u
#pragma unroll
        for (int q = 0; q < 16; ++q) u[q] = row[j + q];
#pragma unroll
        for (int q = 0; q < 16; ++q) tv[q] = t4[u[q]];
#pragma unroll
        for (int q = 0; q < 16; ++q)
            acc = __fadd_rn(acc, __fmul_rn(tv[q], nv[q]));
    }
    for (; j + 4 <= dv; j += 4) {
        int u[4]; float nv[4], tv[4];
#pragma unroll
        for (int q = 0; q < 4; ++q) nv[q] = nr[j + q];
#pragma unroll
        for (int q = 0; q < 4; ++q) u[q] = row[j + q];
#pragma unroll
        for (int q = 0; q < 4; ++q) tv[q] = t4[u[q]];
#pragma unroll
        for (int q = 0; q < 4; ++q)
            acc = __fadd_rn(acc, __fmul_rn(tv[q], nv[q]));
    }
    for (; j < dv; ++j)
        acc = __fadd_rn(acc, __fmul_rn(t4[row[j]], nr[j]));
    acc = __fadd_rn(acc, __fmul_rn(t4[v], __fmul_rn(dsv, dsv)));
    h4[v] = xla_tanhf(__fadd_rn(acc, b4[0]));
}

// ------- per-graph stable top-300 sort on fp32 keys (bitonic, 512 in LDS) -----
__global__ __launch_bounds__(512) void sort_k(const float* __restrict__ h4,
                                              int* __restrict__ order) {
    __shared__ unsigned int kv[512];
    __shared__ int ki[512];
    int tid = threadIdx.x, g = blockIdx.x;
    unsigned int key = 0xFFFFFFFFu;
    if (tid < 400) {
        unsigned int u = __float_as_uint(h4[g * 400 + tid]);
        u = (u & 0x80000000u) ? ~u : (u | 0x80000000u);   // ascending map
        key = ~u;                                          // descending
    }
    kv[tid] = key; ki[tid] = tid;
    __syncthreads();
    for (int size = 2; size <= 512; size <<= 1) {
        for (int stride = size >> 1; stride > 0; stride >>= 1) {
            int p = tid ^ stride;
            if (p > tid) {
                bool asc = ((tid & size) == 0);
                unsigned int a = kv[tid], b = kv[p];
                int ia = ki[tid], ib = ki[p];
                bool gt = (a > b) || (a == b && ia > ib);   // stable tie-break
                if (gt == asc) { kv[tid] = b; kv[p] = a; ki[tid] = ib; ki[p] = ia; }
            }
            __syncthreads();
        }
    }
    if (tid < Kk) order[g * Kk + tid] = ki[tid];
}

// ---------------- conv1: z1[b,c,k] = relu(cb1[c] + sum_d feat[n,d]*cw1[c,d]) --
__global__ __launch_bounds__(128) void conv1_k(const float* __restrict__ h1,
                                               const float* __restrict__ h2,
                                               const float* __restrict__ h3,
                                               const float* __restrict__ h4,
                                               const int* __restrict__ order,
                                               const float* __restrict__ cw1,
                                               const float* __restrict__ cb1,
                                               float* __restrict__ z1) {
    __shared__ double wt[193 * 16];   // transposed [d][c]
    int tid = threadIdx.x, b = blockIdx.y;
    for (int i = tid; i < 193 * 16; i += 128) {
        int c = i / 193, d = i % 193;
        wt[d * 16 + c] = (double)cw1[i];
    }
    __syncthreads();
    int kpos = blockIdx.x * 128 + tid;
    if (kpos >= Kk) return;
    int n = b * 400 + order[b * Kk + kpos];
    double acc[16];
#pragma unroll
    for (int c = 0; c < 16; ++c) acc[c] = (double)cb1[c];
    const float* bases[3] = {h1 + (size_t)n * 64, h2 + (size_t)n * 64, h3 + (size_t)n * 64};
    for (int r = 0; r < 3; ++r) {
        const float* p = bases[r];
        for (int d = 0; d < 64; ++d) {
            double xv = (double)p[d];
            const double* wp = &wt[((size_t)r * 64 + d) * 16];
#pragma unroll
            for (int c = 0; c < 16; ++c) acc[c] += xv * wp[c];
        }
    }
    double xl = (double)h4[n];
    {
        const double* wp = &wt[192 * 16];
#pragma unroll
        for (int c = 0; c < 16; ++c) acc[c] += xl * wp[c];
    }
#pragma unroll
    for (int c = 0; c < 16; ++c)
        z1[((size_t)b * 16 + c) * 300 + kpos] = (float)fmax(acc[c], 0.0);
}

// ------- fused tail: maxpool/2 -> conv2(16->32,k5)+relu -> MLP, per graph ------
__global__ __launch_bounds__(256) void tail_k(const float* __restrict__ z1,
                                              const float* __restrict__ cw2,
                                              const float* __restrict__ cb2,
                                              const float* __restrict__ mw1,
                                              const float* __restrict__ mb1,
                                              const float* __restrict__ mw2,
                                              const float* __restrict__ mb2,
                                              float* __restrict__ out) {
    __shared__ float lz[16 * 150];
    __shared__ float lw[2560];
    __shared__ float lz3[4672];
    __shared__ double red[256];
    __shared__ double s4[32];
    int b = blockIdx.x, tid = threadIdx.x;
    for (int i = tid; i < 2400; i += 256) {
        int bc = i / 150, j = i % 150;
        const float* zp = z1 + ((size_t)b * 16 + bc) * 300 + 2 * j;
        lz[i] = fmaxf(zp[0], zp[1]);
    }
    for (int i = tid; i < 2560; i += 256) lw[i] = cw2[i];
    __syncthreads();
    for (int o = tid; o < 4672; o += 256) {
        int co = o / 146, j = o % 146;
        float acc = cb2[co];
#pragma unroll
        for (int ci = 0; ci < 16; ++ci)
#pragma unroll
            for (int tt = 0; tt < 5; ++tt)
                acc += lz[ci * 150 + j + tt] * lw[co * 80 + ci * 5 + tt];
        lz3[o] = fmaxf(acc, 0.f);
    }
    __syncthreads();
    int o = tid & 31, part = tid >> 5;   // 8 parts x 584
    double acc = 0.0;
    for (int i = part * 584; i < (part + 1) * 584; ++i)
        acc += (double)lz3[i] * (double)mw1[(size_t)i * 32 + o];
    red[tid] = acc;
    __syncthreads();
    if (tid < 32) {
        double s = 0.0;
#pragma unroll
        for (int p = 0; p < 8; ++p) s += red[p * 32 + tid];
        s4[tid] = fmax(s + (double)mb1[tid], 0.0);
    }
    __syncthreads();
    if (tid < 2) {
        double s = (double)mb2[tid];
#pragma unroll
        for (int j = 0; j < 32; ++j) s += s4[j] * (double)mw2[j * 2 + tid];
        out[b * 2 + tid] = (float)s;
    }
}

extern "C" void kernel_launch(void* const* d_in, const int* in_sizes, int n_in,
                              void* d_out, int out_size, void* d_ws, size_t ws_size,
                              hipStream_t stream) {
    const float* x   = (const float*)d_in[0];
    const int*   ei  = (const int*)d_in[1];
    const float* W1  = (const float*)d_in[2];  const float* b1  = (const float*)d_in[3];
    const float* W2  = (const float*)d_in[4];  const float* b2  = (const float*)d_in[5];
    const float* W3  = (const float*)d_in[6];  const float* b3  = (const float*)d_in[7];
    const float* W4  = (const float*)d_in[8];  const float* b4  = (const float*)d_in[9];
    const float* cw1 = (const float*)d_in[10]; const float* cb1 = (const float*)d_in[11];
    const float* cw2 = (const float*)d_in[12]; const float* cb2 = (const float*)d_in[13];
    const float* mw1 = (const float*)d_in[14]; const float* mb1 = (const float*)d_in[15];
    const float* mw2 = (const float*)d_in[16]; const float* mb2 = (const float*)d_in[17];
    float* out = (float*)d_out;

    const size_t N64 = (size_t)Nn * 64;
    float* t    = (float*)d_ws;           // [N,64] transform scratch (fp32)
    float* h1   = t + N64;
    float* h2   = h1 + N64;
    float* h3   = h2 + N64;
    float* t4   = h3 + N64;               // [N]
    float* h4   = t4 + Nn;                // [N]
    float* dis  = h4 + Nn;                // [N]
    int*   degc = (int*)(dis + Nn);       // [N] compact degree
    int*   fill = degc + Nn;              // [N*16] padded atomic counters
    int*   csr  = fill + (size_t)Nn * 16; // [N,CAP]
    float* nrm  = (float*)(csr + (size_t)Nn * CAP);  // [N,CAP] norm per slot
    int*   order = (int*)(nrm + N64);
    float* z1 = (float*)t;                // aliases t (free after agg3 consumed it)

    hipMemsetAsync(fill, 0, sizeof(int) * (size_t)Nn * 16, stream);

    scat_k<<<Ee / 512, 256, 0, stream>>>(ei, fill, csr);
    dis_k<<<Nn / 256, 256, 0, stream>>>(fill, dis, degc);

    gemm_w32<25><<<Nn / 32, 64, 0, stream>>>(x, W1, t);
    agg64_k<1><<<Nn / 4, 256, 0, stream>>>(t, b1, dis, degc, ei, csr, nrm, h1, nullptr, nullptr);
    gemm_w32<4> <<<Nn / 32, 64, 0, stream>>>(h1, W2, t);
    agg64_k<0><<<Nn / 4, 256, 0, stream>>>(t, b2, dis, degc, ei, csr, nrm, h2, nullptr, nullptr);
    gemm_w32<4> <<<Nn / 32, 64, 0, stream>>>(h2, W3, t);
    agg64_k<0><<<Nn / 4, 256, 0, stream>>>(t, b3, dis, degc, ei, csr, nrm, h3, W4, t4);

    agg1_k<<<Nn / 256, 256, 0, stream>>>(t4, dis, degc, csr, nrm, b4, h4);

    sort_k<<<Bb, 512, 0, stream>>>(h4, order);
    conv1_k<<<dim3(3, Bb), 128, 0, stream>>>(h1, h2, h3, h4, order, cw1, cb1, z1);
    tail_k<<<Bb, 256, 0, stream>>>(z1, cw2, cb2, mw1, mb1, mw2, mb2, out);
}

// Round 7
// 935.970 us; speedup vs baseline: 1.1532x; 1.1532x over previous
//
#include <hip/hip_runtime.h>
#include <cstdint>
#include <cstddef>

#define Nn 102400
#define Ff 400
#define Ee 1638400
#define Kk 300
#define Bb 256
#define CAP 64

// XLA/Eigen f32 rational tanh approximation (ElementalIrEmitter::EmitTanh).
// Evaluated with UNFUSED mul/add (XLA emits plain fmul/fadd, no contraction),
// so CPU(np-ref) and this agree bitwise given bit-identical inputs.
__device__ __forceinline__ float xla_tanhf(float x) {
    const float c = 7.90531110763549805f;
    float xc = fminf(fmaxf(x, -c), c);
    float x2 = __fmul_rn(xc, xc);
    float p = -2.76076847742355e-16f;
    p = __fadd_rn(__fmul_rn(p, x2),  2.00018790482477e-13f);
    p = __fadd_rn(__fmul_rn(p, x2), -8.60467152213735e-11f);
    p = __fadd_rn(__fmul_rn(p, x2),  5.12229709037114e-08f);
    p = __fadd_rn(__fmul_rn(p, x2),  1.48572235717979e-05f);
    p = __fadd_rn(__fmul_rn(p, x2),  6.37261928875436e-04f);
    p = __fadd_rn(__fmul_rn(p, x2),  4.89352455891786e-03f);
    p = __fmul_rn(p, xc);
    float q = 1.19825839466702e-06f;
    q = __fadd_rn(__fmul_rn(q, x2), 1.18534705686654e-04f);
    q = __fadd_rn(__fmul_rn(q, x2), 2.26843463243900e-03f);
    q = __fadd_rn(__fmul_rn(q, x2), 4.89352518554385e-03f);
    float r = __fdiv_rn(p, q);
    return (fabsf(x) < 0.0004f) ? x : r;
}

// ---------------- CSR build: 2 edges/thread, padded fill (64B/counter) -------
__global__ void scat_k(const int* __restrict__ ei, int* __restrict__ fill,
                       int* __restrict__ csr) {
    int g = blockIdx.x * 256 + threadIdx.x;
    int2 d2 = *(const int2*)(ei + Ee + 2 * g);
    int e0 = 2 * g, e1 = 2 * g + 1;
    int p0 = atomicAdd(&fill[(size_t)d2.x * 16], 1);
    int p1 = atomicAdd(&fill[(size_t)d2.y * 16], 1);
    if (p0 < CAP) csr[(size_t)d2.x * CAP + p0] = e0;   // edge id, not src
    if (p1 < CAP) csr[(size_t)d2.y * CAP + p1] = e1;
}

// dis = 1/sqrt(deg+1) fp32 (two correctly-rounded ops = XLA-CPU rsqrt
// lowering); compact degree out of the padded counters.
__global__ void dis_k(const int* __restrict__ fill, float* __restrict__ dis,
                      int* __restrict__ degc) {
    int v = blockIdx.x * 256 + threadIdx.x;
    if (v >= Nn) return;
    int d = fill[(size_t)v * 16];
    degc[v] = d;
    dis[v] = 1.0f / sqrtf((float)(d + 1));   // +1 self loop
}

// ---- 2-wave fp32 GEMM: [M,K]@[K,64], 32x64 tile per 128-thread block, the
// tile's COLUMNS split across 2 waves (wave w -> cols w*32..+31). A and B are
// staged into LDS ONCE per tile (no extra HBM traffic vs the 1-wave form);
// wave count doubles to 6400 (~25 waves/CU vs the grid-limited 12.5 that
// pinned r2-r6 at 26-29% occupancy / 19% VALUBusy). Per output element: ONE
// fma per k, k strictly ascending -> replicates Eigen gebp, bit-identical.
template <int CH>   // K = 16*CH
__global__ __launch_bounds__(128) void gemm_2w(const float* __restrict__ A,
                                               const float* __restrict__ B,
                                               float* __restrict__ C) {
    constexpr int K = 16 * CH;
    __shared__ __align__(16) float As[16 * 32];
    __shared__ __align__(16) float Bs[16 * 68];
    int tid = threadIdx.x;
    int w = tid >> 6;             // wave id: cols w*32..w*32+31
    int lane = tid & 63;
    int tx = lane & 15;           // col pair {w*32+2tx, w*32+2tx+1}
    int ty = lane >> 4;           // rows ty*8..+7
    int base = blockIdx.x * 32;
    int sr = tid >> 2, sq = tid & 3;        // A staging: row sr(0..31), k-quad sq
    int bk = tid >> 3, bn = (tid & 7) * 8;  // B staging: k-row bk(0..15), 8 cols
    float acc[8][2] = {};
    for (int ch = 0; ch < CH; ++ch) {
        int k0 = ch * 16;
        float4 av = *(const float4*)(A + (size_t)(base + sr) * K + k0 + sq * 4);
        const float* bp = B + (size_t)(k0 + bk) * 64 + bn;
        float4 b0 = *(const float4*)(bp);
        float4 b1 = *(const float4*)(bp + 4);
        __syncthreads();
        As[(sq * 4 + 0) * 32 + sr] = av.x;
        As[(sq * 4 + 1) * 32 + sr] = av.y;
        As[(sq * 4 + 2) * 32 + sr] = av.z;
        As[(sq * 4 + 3) * 32 + sr] = av.w;
        *(float4*)&Bs[bk * 68 + bn]     = b0;
        *(float4*)&Bs[bk * 68 + bn + 4] = b1;
        __syncthreads();
#pragma unroll
        for (int kk = 0; kk < 16; ++kk) {
            float4 f0 = *(const float4*)&As[kk * 32 + ty * 8];
            float4 f1 = *(const float4*)&As[kk * 32 + ty * 8 + 4];
            float2 bb = *(const float2*)&Bs[kk * 68 + w * 32 + tx * 2];
            float av8[8] = {f0.x, f0.y, f0.z, f0.w, f1.x, f1.y, f1.z, f1.w};
#pragma unroll
            for (int r = 0; r < 8; ++r) {
                acc[r][0] = fmaf(av8[r], bb.x, acc[r][0]);
                acc[r][1] = fmaf(av8[r], bb.y, acc[r][1]);
            }
        }
    }
#pragma unroll
    for (int r = 0; r < 8; ++r) {
        float* cp = C + (size_t)(base + ty * 8 + r) * 64 + w * 32 + tx * 2;
        *(float2*)cp = make_float2(acc[r][0], acc[r][1]);
    }
}

// ---- single-wave fp32 GEMM (r2-exact, known-good for small K): 32x64 tile,
// 64 thr, 8x4/thread, single-buffered; workgroup == 1 wave so __syncthreads()
// lowers to s_waitcnt only. ONE fma per k, ascending -> Eigen gebp.
template <int CH>   // K = 16*CH
__global__ __launch_bounds__(64) void gemm_w32(const float* __restrict__ A,
                                               const float* __restrict__ B,
                                               float* __restrict__ C) {
    constexpr int K = 16 * CH;
    __shared__ __align__(16) float As[16 * 32];
    __shared__ __align__(16) float Bs[16][68];
    int tid = threadIdx.x;
    int tx = tid & 15;            // cols {tx*2, tx*2+1, 32+tx*2, 33+tx*2}
    int ty = tid >> 4;            // rows ty*8..+7
    int base = blockIdx.x * 32;
    int sr = tid >> 1, sh = tid & 1;        // A staging: row sr, k-half sh
    int bk = tid >> 2, bn = (tid & 3) * 16; // B staging: k-row bk, 16 cols
    float acc[8][4] = {};
    for (int ch = 0; ch < CH; ++ch) {
        int k0 = ch * 16;
        const float* ap = A + (size_t)(base + sr) * K + k0 + sh * 8;
        float4 v0 = *(const float4*)(ap);
        float4 v1 = *(const float4*)(ap + 4);
        float a8[8] = {v0.x, v0.y, v0.z, v0.w, v1.x, v1.y, v1.z, v1.w};
        float4 bv4[4];
        const float* bp = B + (size_t)(k0 + bk) * 64 + bn;
#pragma unroll
        for (int q = 0; q < 4; ++q) bv4[q] = *(const float4*)(bp + q * 4);
        __syncthreads();   // wave-level: s_waitcnt only
#pragma unroll
        for (int q = 0; q < 8; ++q) As[(sh * 8 + q) * 32 + sr] = a8[q];
#pragma unroll
        for (int q = 0; q < 4; ++q) *(float4*)&Bs[bk][bn + q * 4] = bv4[q];
        __syncthreads();
#pragma unroll
        for (int kk = 0; kk < 16; ++kk) {
            float4 f0 = *(const float4*)&As[kk * 32 + ty * 8];
            float4 f1 = *(const float4*)&As[kk * 32 + ty * 8 + 4];
            float av[8] = {f0.x, f0.y, f0.z, f0.w, f1.x, f1.y, f1.z, f1.w};
            float2 b01 = *(const float2*)&Bs[kk][tx * 2];
            float2 b23 = *(const float2*)&Bs[kk][32 + tx * 2];
            float bv[4] = {b01.x, b01.y, b23.x, b23.y};
#pragma unroll
            for (int r = 0; r < 8; ++r)
#pragma unroll
                for (int c = 0; c < 4; ++c) acc[r][c] = fmaf(av[r], bv[c], acc[r][c]);
        }
    }
#pragma unroll
    for (int r = 0; r < 8; ++r) {
        float* cp = C + (size_t)(base + ty * 8 + r) * 64;
        *(float2*)(cp + tx * 2)      = make_float2(acc[r][0], acc[r][1]);
        *(float2*)(cp + 32 + tx * 2) = make_float2(acc[r][2], acc[r][3]);
    }
}

// ------- out = xla_tanh(b + segment_sum(norm_e * t[src_e]) ), fp32 exact-order.
// PHASE 1 additionally does what sortrow_k used to do: bitonic-sort the
// edge-id row (ascending = segment_sum scatter order), gather src = ei[key]
// and dis[src], write the sorted src row + nrm for PHASE 0 reuse. Rows
// padded to a multiple of 32 with nr=0, u=v: fadd(acc, fmul(tv,0)) == acc
// exactly, so remainder loops vanish. fma order UNCHANGED: ascending slots,
// then self-loop.
template <int PHASE>
__global__ __launch_bounds__(256, 4) void agg64_k(const float* __restrict__ t,
                                                  const float* __restrict__ bias,
                                                  const float* __restrict__ dis,
                                                  const int* __restrict__ degc,
                                                  const int* __restrict__ ei,
                                                  int* __restrict__ csr,
                                                  float* __restrict__ nrm,
                                                  float* __restrict__ out,
                                                  const float* __restrict__ W4,
                                                  float* __restrict__ t4) {
    __shared__ int   sidx[4][64];
    __shared__ float snr[4][64];
    int lane = threadIdx.x & 63;
    int wv = __builtin_amdgcn_readfirstlane(threadIdx.x >> 6);
    int v = blockIdx.x * 4 + wv;
    int dv = __builtin_amdgcn_readfirstlane(min(degc[v], CAP));
    float dsv = dis[v];
    float tself = t[(size_t)v * 64 + lane];   // early, independent
    float bsl = bias[lane];                   // early, independent
    int idxl;
    float nr;
    if (PHASE == 1) {
        int key = (lane < dv) ? csr[(size_t)v * CAP + lane] : 0x7FFFFFFF;
        // 64-lane bitonic sort ascending (identical network to old sortrow_k;
        // edge ids are distinct -> deterministic order)
#pragma unroll
        for (int k = 2; k <= 64; k <<= 1) {
#pragma unroll
            for (int j = k >> 1; j; j >>= 1) {
                int other = __shfl_xor(key, j);
                bool up = ((lane & k) == 0);
                bool lower = ((lane & j) == 0);
                key = (lower == up) ? min(key, other) : max(key, other);
            }
        }
        idxl = v;                                    // pad u = v
        if (lane < dv) idxl = ei[key];               // src of that edge
        nr = (lane < dv) ? __fmul_rn(dis[idxl], dsv) : 0.0f;   // pad nr = 0
        csr[(size_t)v * CAP + lane] = idxl;          // sorted src row
        nrm[(size_t)v * 64 + lane] = nr;
    } else {
        idxl = (lane < dv) ? csr[(size_t)v * CAP + lane] : v;
        nr = nrm[(size_t)v * 64 + lane];             // pads are 0
    }
    sidx[wv][lane] = idxl;
    snr[wv][lane] = nr;
    // in-order DS per wave: reads below see the writes above (validated r3/r4)
    int dvp = (dv + 31) & ~31;                // 0, 32, or 64
    float acc = 0.0f;
    for (int j = 0; j < dvp; j += 32) {
        float tv[32], nv[32];
#pragma unroll
        for (int q = 0; q < 32; ++q) {
            int u = __builtin_amdgcn_readfirstlane(sidx[wv][j + q]);
            tv[q] = t[(size_t)u * 64 + lane];
        }
#pragma unroll
        for (int q = 0; q < 32; ++q) nv[q] = snr[wv][j + q];
#pragma unroll
        for (int q = 0; q < 32; ++q)
            acc = __fadd_rn(acc, __fmul_rn(tv[q], nv[q]));   // pads: +0, exact
    }
    // self-loop last (ref appends loops after edges)
    acc = __fadd_rn(acc, __fmul_rn(tself, __fmul_rn(dsv, dsv)));
    float res = xla_tanhf(__fadd_rn(acc, bsl));
    out[(size_t)v * 64 + lane] = res;
    if (W4 != nullptr) {
        // h3 . W4, sequential k=0..63 with FMA (one accumulator)
        float w4l = W4[lane];
        float a4 = 0.0f;
#pragma unroll
        for (int k = 0; k < 64; ++k) {
            float hk = __shfl(res, k);
            float wk = __shfl(w4l, k);
            a4 = fmaf(hk, wk, a4);
        }
        if (lane == 0) t4[v] = a4;
    }
}

__global__ void agg1_k(const float* __restrict__ t4, const float* __restrict__ dis,
                       const int* __restrict__ degc, const int* __restrict__ csr,
                       const float* __restrict__ nrm,
                       const float* __restrict__ b4, float* __restrict__ h4) {
    int v = blockIdx.x * 256 + threadIdx.x;
    if (v >= Nn) return;
    int dv = min(degc[v], CAP);
    float dsv = dis[v];
    const int* row = csr + (size_t)v * CAP;
    const float* nr = nrm + (size_t)v * 64;
    float acc = 0.0f;
    int j = 0;
    for (; j + 16 <= dv; j += 16) {
        int u[16]; float nv[16], tv[16];
#pragma unroll
        for (int q = 0; q < 16; ++q) nv[q] = nr[j + q];     // independent of u
#pragma unroll
        for (int q = 0; q < 16; ++q) u[q] = row[j + q];
#pragma unroll
        for (int q = 0; q < 16; ++q) tv[q] = t4[u[q]];
#pragma unroll
        for (int q = 0; q < 16; ++q)
            acc = __fadd_rn(acc, __fmul_rn(tv[q], nv[q]));
    }
    for (; j + 4 <= dv; j += 4) {
        int u[4]; float nv[4], tv[4];
#pragma unroll
        for (int q = 0; q < 4; ++q) nv[q] = nr[j + q];
#pragma unroll
        for (int q = 0; q < 4; ++q) u[q] = row[j + q];
#pragma unroll
        for (int q = 0; q < 4; ++q) tv[q] = t4[u[q]];
#pragma unroll
        for (int q = 0; q < 4; ++q)
            acc = __fadd_rn(acc, __fmul_rn(tv[q], nv[q]));
    }
    for (; j < dv; ++j)
        acc = __fadd_rn(acc, __fmul_rn(t4[row[j]], nr[j]));
    acc = __fadd_rn(acc, __fmul_rn(t4[v], __fmul_rn(dsv, dsv)));
    h4[v] = xla_tanhf(__fadd_rn(acc, b4[0]));
}

// ------- per-graph stable top-300 sort on fp32 keys (bitonic, 512 in LDS) -----
__global__ __launch_bounds__(512) void sort_k(const float* __restrict__ h4,
                                              int* __restrict__ order) {
    __shared__ unsigned int kv[512];
    __shared__ int ki[512];
    int tid = threadIdx.x, g = blockIdx.x;
    unsigned int key = 0xFFFFFFFFu;
    if (tid < 400) {
        unsigned int u = __float_as_uint(h4[g * 400 + tid]);
        u = (u & 0x80000000u) ? ~u : (u | 0x80000000u);   // ascending map
        key = ~u;                                          // descending
    }
    kv[tid] = key; ki[tid] = tid;
    __syncthreads();
    for (int size = 2; size <= 512; size <<= 1) {
        for (int stride = size >> 1; stride > 0; stride >>= 1) {
            int p = tid ^ stride;
            if (p > tid) {
                bool asc = ((tid & size) == 0);
                unsigned int a = kv[tid], b = kv[p];
                int ia = ki[tid], ib = ki[p];
                bool gt = (a > b) || (a == b && ia > ib);   // stable tie-break
                if (gt == asc) { kv[tid] = b; kv[p] = a; ki[tid] = ib; ki[p] = ia; }
            }
            __syncthreads();
        }
    }
    if (tid < Kk) order[g * Kk + tid] = ki[tid];
}

// ---------------- conv1: z1[b,c,k] = relu(cb1[c] + sum_d feat[n,d]*cw1[c,d]) --
__global__ __launch_bounds__(128) void conv1_k(const float* __restrict__ h1,
                                               const float* __restrict__ h2,
                                               const float* __restrict__ h3,
                                               const float* __restrict__ h4,
                                               const int* __restrict__ order,
                                               const float* __restrict__ cw1,
                                               const float* __restrict__ cb1,
                                               float* __restrict__ z1) {
    __shared__ double wt[193 * 16];   // transposed [d][c]
    int tid = threadIdx.x, b = blockIdx.y;
    for (int i = tid; i < 193 * 16; i += 128) {
        int c = i / 193, d = i % 193;
        wt[d * 16 + c] = (double)cw1[i];
    }
    __syncthreads();
    int kpos = blockIdx.x * 128 + tid;
    if (kpos >= Kk) return;
    int n = b * 400 + order[b * Kk + kpos];
    double acc[16];
#pragma unroll
    for (int c = 0; c < 16; ++c) acc[c] = (double)cb1[c];
    const float* bases[3] = {h1 + (size_t)n * 64, h2 + (size_t)n * 64, h3 + (size_t)n * 64};
    for (int r = 0; r < 3; ++r) {
        const float* p = bases[r];
        for (int d = 0; d < 64; ++d) {
            double xv = (double)p[d];
            const double* wp = &wt[((size_t)r * 64 + d) * 16];
#pragma unroll
            for (int c = 0; c < 16; ++c) acc[c] += xv * wp[c];
        }
    }
    double xl = (double)h4[n];
    {
        const double* wp = &wt[192 * 16];
#pragma unroll
        for (int c = 0; c < 16; ++c) acc[c] += xl * wp[c];
    }
#pragma unroll
    for (int c = 0; c < 16; ++c)
        z1[((size_t)b * 16 + c) * 300 + kpos] = (float)fmax(acc[c], 0.0);
}

// ------- fused tail: maxpool/2 -> conv2(16->32,k5)+relu -> MLP, per graph ------
__global__ __launch_bounds__(256) void tail_k(const float* __restrict__ z1,
                                              const float* __restrict__ cw2,
                                              const float* __restrict__ cb2,
                                              const float* __restrict__ mw1,
                                              const float* __restrict__ mb1,
                                              const float* __restrict__ mw2,
                                              const float* __restrict__ mb2,
                                              float* __restrict__ out) {
    __shared__ float lz[16 * 150];
    __shared__ float lw[2560];
    __shared__ float lz3[4672];
    __shared__ double red[256];
    __shared__ double s4[32];
    int b = blockIdx.x, tid = threadIdx.x;
    for (int i = tid; i < 2400; i += 256) {
        int bc = i / 150, j = i % 150;
        const float* zp = z1 + ((size_t)b * 16 + bc) * 300 + 2 * j;
        lz[i] = fmaxf(zp[0], zp[1]);
    }
    for (int i = tid; i < 2560; i += 256) lw[i] = cw2[i];
    __syncthreads();
    for (int o = tid; o < 4672; o += 256) {
        int co = o / 146, j = o % 146;
        float acc = cb2[co];
#pragma unroll
        for (int ci = 0; ci < 16; ++ci)
#pragma unroll
            for (int tt = 0; tt < 5; ++tt)
                acc += lz[ci * 150 + j + tt] * lw[co * 80 + ci * 5 + tt];
        lz3[o] = fmaxf(acc, 0.f);
    }
    __syncthreads();
    int o = tid & 31, part = tid >> 5;   // 8 parts x 584
    double acc = 0.0;
    for (int i = part * 584; i < (part + 1) * 584; ++i)
        acc += (double)lz3[i] * (double)mw1[(size_t)i * 32 + o];
    red[tid] = acc;
    __syncthreads();
    if (tid < 32) {
        double s = 0.0;
#pragma unroll
        for (int p = 0; p < 8; ++p) s += red[p * 32 + tid];
        s4[tid] = fmax(s + (double)mb1[tid], 0.0);
    }
    __syncthreads();
    if (tid < 2) {
        double s = (double)mb2[tid];
#pragma unroll
        for (int j = 0; j < 32; ++j) s += s4[j] * (double)mw2[j * 2 + tid];
        out[b * 2 + tid] = (float)s;
    }
}

extern "C" void kernel_launch(void* const* d_in, const int* in_sizes, int n_in,
                              void* d_out, int out_size, void* d_ws, size_t ws_size,
                              hipStream_t stream) {
    const float* x   = (const float*)d_in[0];
    const int*   ei  = (const int*)d_in[1];
    const float* W1  = (const float*)d_in[2];  const float* b1  = (const float*)d_in[3];
    const float* W2  = (const float*)d_in[4];  const float* b2  = (const float*)d_in[5];
    const float* W3  = (const float*)d_in[6];  const float* b3  = (const float*)d_in[7];
    const float* W4  = (const float*)d_in[8];  const float* b4  = (const float*)d_in[9];
    const float* cw1 = (const float*)d_in[10]; const float* cb1 = (const float*)d_in[11];
    const float* cw2 = (const float*)d_in[12]; const float* cb2 = (const float*)d_in[13];
    const float* mw1 = (const float*)d_in[14]; const float* mb1 = (const float*)d_in[15];
    const float* mw2 = (const float*)d_in[16]; const float* mb2 = (const float*)d_in[17];
    float* out = (float*)d_out;

    const size_t N64 = (size_t)Nn * 64;
    float* t    = (float*)d_ws;           // [N,64] transform scratch (fp32)
    float* h1   = t + N64;
    float* h2   = h1 + N64;
    float* h3   = h2 + N64;
    float* t4   = h3 + N64;               // [N]
    float* h4   = t4 + Nn;                // [N]
    float* dis  = h4 + Nn;                // [N]
    int*   degc = (int*)(dis + Nn);       // [N] compact degree
    int*   fill = degc + Nn;              // [N*16] padded atomic counters
    int*   csr  = fill + (size_t)Nn * 16; // [N,CAP]
    float* nrm  = (float*)(csr + (size_t)Nn * CAP);  // [N,CAP] norm per slot
    int*   order = (int*)(nrm + N64);
    float* z1 = (float*)t;                // aliases t (free after agg3 consumed it)

    hipMemsetAsync(fill, 0, sizeof(int) * (size_t)Nn * 16, stream);

    scat_k<<<Ee / 512, 256, 0, stream>>>(ei, fill, csr);
    dis_k<<<Nn / 256, 256, 0, stream>>>(fill, dis, degc);

    gemm_2w<25><<<Nn / 32, 128, 0, stream>>>(x, W1, t);
    agg64_k<1><<<Nn / 4, 256, 0, stream>>>(t, b1, dis, degc, ei, csr, nrm, h1, nullptr, nullptr);
    gemm_w32<4><<<Nn / 32, 64, 0, stream>>>(h1, W2, t);
    agg64_k<0><<<Nn / 4, 256, 0, stream>>>(t, b2, dis, degc, ei, csr, nrm, h2, nullptr, nullptr);
    gemm_w32<4><<<Nn / 32, 64, 0, stream>>>(h2, W3, t);
    agg64_k<0><<<Nn / 4, 256, 0, stream>>>(t, b3, dis, degc, ei, csr, nrm, h3, W4, t4);

    agg1_k<<<Nn / 256, 256, 0, stream>>>(t4, dis, degc, csr, nrm, b4, h4);

    sort_k<<<Bb, 512, 0, stream>>>(h4, order);
    conv1_k<<<dim3(3, Bb), 128, 0, stream>>>(h1, h2, h3, h4, order, cw1, cb1, z1);
    tail_k<<<Bb, 256, 0, stream>>>(z1, cw2, cb2, mw1, mb1, mw2, mb2, out);
}